// Round 1
// baseline (1119.296 us; speedup 1.0000x reference)
//
#include <hip/hip_runtime.h>
#include <math.h>

#define NROW 8192
#define DIM  128

// ---------------- row normalize: one wave per row ----------------
__global__ void rownorm_kernel(const float* __restrict__ X, float* __restrict__ dn) {
    int row = blockIdx.x;
    int lane = threadIdx.x;            // 64 lanes
    const float2* x2 = reinterpret_cast<const float2*>(X + (size_t)row * DIM);
    float2 v = x2[lane];
    float s = v.x * v.x + v.y * v.y;
    #pragma unroll
    for (int off = 32; off > 0; off >>= 1) s += __shfl_xor(s, off);
    float r = 1.0f / sqrtf(s);
    float2 o; o.x = v.x * r; o.y = v.y * r;
    reinterpret_cast<float2*>(dn + (size_t)row * DIM)[lane] = o;
}

// ---------------- build K = 10*dot - 10 (diag -10000) ----------------
#define BT 64
#define LDSP 132   // 128 + 4 pad: bank = (4*row + k) % 32
__launch_bounds__(256, 2)
__global__ void buildK_kernel(const float* __restrict__ dn, float* __restrict__ K) {
    __shared__ float As[BT][LDSP];
    __shared__ float Bs[BT][LDSP];
    int bi = blockIdx.y, bj = blockIdx.x;
    int tid = threadIdx.x;

    const float4* gA = reinterpret_cast<const float4*>(dn + (size_t)bi * BT * DIM);
    const float4* gB = reinterpret_cast<const float4*>(dn + (size_t)bj * BT * DIM);
    #pragma unroll
    for (int s = 0; s < 8; ++s) {
        int idx = tid + s * 256;           // 0..2047
        int r  = idx >> 5;                 // row 0..63
        int k4 = idx & 31;                 // float4 col 0..31
        float4 a = gA[idx];
        float4 b = gB[idx];
        *reinterpret_cast<float4*>(&As[r][k4 * 4]) = a;
        *reinterpret_cast<float4*>(&Bs[r][k4 * 4]) = b;
    }
    __syncthreads();

    int c = tid & 15;          // cols {c + 16j}
    int r = tid >> 4;          // rows {r + 16i}  (r in 0..15; 0..3 within a wave)
    float acc[4][4] = {};
    for (int k0 = 0; k0 < DIM; k0 += 4) {
        float4 a[4], b[4];
        #pragma unroll
        for (int i = 0; i < 4; ++i) a[i] = *reinterpret_cast<const float4*>(&As[r + 16 * i][k0]);
        #pragma unroll
        for (int j = 0; j < 4; ++j) b[j] = *reinterpret_cast<const float4*>(&Bs[c + 16 * j][k0]);
        #pragma unroll
        for (int i = 0; i < 4; ++i)
            #pragma unroll
            for (int j = 0; j < 4; ++j)
                acc[i][j] += a[i].x * b[j].x + a[i].y * b[j].y + a[i].z * b[j].z + a[i].w * b[j].w;
    }

    int row0 = bi * BT, col0 = bj * BT;
    #pragma unroll
    for (int i = 0; i < 4; ++i) {
        int gr = row0 + r + 16 * i;
        #pragma unroll
        for (int j = 0; j < 4; ++j) {
            int gc = col0 + c + 16 * j;
            float kv = 10.0f * acc[i][j] - 10.0f;
            if (gr == gc) kv = -10000.0f;
            K[(size_t)gr * NROW + gc] = kv;
        }
    }
}

// ---------------- row LSE: out[i] = -log(sum_j exp(K[i][j] + vin[j])) ----------------
__launch_bounds__(256)
__global__ void lse_kernel(const float* __restrict__ K, const float* __restrict__ vin,
                           float* __restrict__ out, float* __restrict__ rmax) {
    int row = blockIdx.x;
    int tid = threadIdx.x;
    const float4* Krow = reinterpret_cast<const float4*>(K + (size_t)row * NROW);
    const float4* V4 = reinterpret_cast<const float4*>(vin);
    float s = 0.0f;
    float m = -3.4e38f;
    #pragma unroll
    for (int w = 0; w < 8; ++w) {
        int j4 = tid + w * 256;
        float4 kk = Krow[j4];
        float4 vv = V4[j4];
        float x0 = kk.x + vv.x, x1 = kk.y + vv.y, x2 = kk.z + vv.z, x3 = kk.w + vv.w;
        s += __expf(x0) + __expf(x1) + __expf(x2) + __expf(x3);
        m = fmaxf(m, fmaxf(fmaxf(x0, x1), fmaxf(x2, x3)));
    }
    #pragma unroll
    for (int off = 32; off > 0; off >>= 1) {
        s += __shfl_xor(s, off);
        m = fmaxf(m, __shfl_xor(m, off));
    }
    __shared__ float ls[4], lm[4];
    int wid = tid >> 6;
    if ((tid & 63) == 0) { ls[wid] = s; lm[wid] = m; }
    __syncthreads();
    if (tid == 0) {
        float S = ls[0] + ls[1] + ls[2] + ls[3];
        float M = fmaxf(fmaxf(lm[0], lm[1]), fmaxf(lm[2], lm[3]));
        out[row] = -__logf(S);
        rmax[row] = M;
    }
}

// ---------------- global max of (v[j] + rmax[j]) -> inv sigmoid scale ----------------
__global__ void maxred_kernel(const float* __restrict__ v, const float* __restrict__ rmax,
                              float* __restrict__ sc) {
    int tid = threadIdx.x;
    float m = -3.4e38f;
    for (int j = tid; j < NROW; j += 256) m = fmaxf(m, v[j] + rmax[j]);
    #pragma unroll
    for (int off = 32; off > 0; off >>= 1) m = fmaxf(m, __shfl_xor(m, off));
    __shared__ float lm[4];
    int wid = tid >> 6;
    if ((tid & 63) == 0) lm[wid] = m;
    __syncthreads();
    if (tid == 0) {
        float M = fmaxf(fmaxf(lm[0], lm[1]), fmaxf(lm[2], lm[3]));
        sc[0] = 1.0f + __expf(-M);   // 1 / sigmoid(M)
    }
}

// ---------------- finalize: out = sigmoid(u_i + K + v_j) * s_inv, diag = 1 ----------------
__launch_bounds__(256)
__global__ void finalize_kernel(float* __restrict__ K, const float* __restrict__ u,
                                const float* __restrict__ v, const float* __restrict__ sc) {
    float s_inv = sc[0];
    const size_t nt4 = (size_t)NROW * NROW / 4;
    size_t stride = (size_t)gridDim.x * blockDim.x;
    for (size_t e = (size_t)blockIdx.x * blockDim.x + threadIdx.x; e < nt4; e += stride) {
        size_t i = e >> 11;                  // row (8192/4 = 2048 float4 per row)
        int j0 = (int)((e & 2047) << 2);     // starting col
        float4 kk = reinterpret_cast<const float4*>(K)[e];
        float4 vv = reinterpret_cast<const float4*>(v)[e & 2047];
        float ui = u[i];
        float x[4];
        x[0] = ui + kk.x + vv.x;
        x[1] = ui + kk.y + vv.y;
        x[2] = ui + kk.z + vv.z;
        x[3] = ui + kk.w + vv.w;
        float o[4];
        #pragma unroll
        for (int t = 0; t < 4; ++t)
            o[t] = s_inv * __builtin_amdgcn_rcpf(1.0f + __expf(-x[t]));
        if (i >= (size_t)j0 && i < (size_t)j0 + 4) o[i - j0] = 1.0f;
        float4 ov; ov.x = o[0]; ov.y = o[1]; ov.z = o[2]; ov.w = o[3];
        reinterpret_cast<float4*>(K)[e] = ov;
    }
}

extern "C" void kernel_launch(void* const* d_in, const int* in_sizes, int n_in,
                              void* d_out, int out_size, void* d_ws, size_t ws_size,
                              hipStream_t stream) {
    const float* X = (const float*)d_in[0];
    float* out = (float*)d_out;
    char* ws = (char*)d_ws;

    float* dn   = (float*)ws;                                  // 8192*128 fp32 = 4 MB
    float* u    = (float*)(ws + (size_t)NROW * DIM * 4);       // 32 KB
    float* v    = u + NROW;                                    // 32 KB
    float* rmax = v + NROW;                                    // 32 KB
    float* sc   = rmax + NROW;                                 // 4 B

    hipMemsetAsync(v, 0, NROW * sizeof(float), stream);
    rownorm_kernel<<<NROW, 64, 0, stream>>>(X, dn);

    dim3 g(NROW / BT, NROW / BT);
    buildK_kernel<<<g, 256, 0, stream>>>(dn, out);

    for (int it = 0; it < 10; ++it) {
        lse_kernel<<<NROW, 256, 0, stream>>>(out, v, u, rmax);  // u = -LSE(K + v)
        lse_kernel<<<NROW, 256, 0, stream>>>(out, u, v, rmax);  // v = -LSE(K^T + u) = row pass (K symmetric)
    }

    maxred_kernel<<<1, 256, 0, stream>>>(v, rmax, sc);
    finalize_kernel<<<4096, 256, 0, stream>>>(out, u, v, sc);
}

// Round 2
// 625.334 us; speedup vs baseline: 1.7899x; 1.7899x over previous
//
#include <hip/hip_runtime.h>
#include <hip/hip_bf16.h>
#include <hip/hip_fp16.h>
#include <math.h>

#define NROW 8192
#define DIM  128

typedef short bf16x8 __attribute__((ext_vector_type(8)));
typedef float f32x4  __attribute__((ext_vector_type(4)));
typedef _Float16 half8 __attribute__((ext_vector_type(8)));

__device__ inline ushort f2bf(float x) { __hip_bfloat16 b = __float2bfloat16(x); return *(ushort*)&b; }
__device__ inline float  bf2f(ushort u) { __hip_bfloat16 b; *(ushort*)&b = u; return __bfloat162float(b); }

// ---------------- row normalize + split into bf16 hi/lo ----------------
__global__ void rownorm_kernel(const float* __restrict__ X,
                               ushort* __restrict__ dn_hi, ushort* __restrict__ dn_lo) {
    int row = blockIdx.x;
    int lane = threadIdx.x;            // 64 lanes
    const float2* x2 = reinterpret_cast<const float2*>(X + (size_t)row * DIM);
    float2 v = x2[lane];
    float s = v.x * v.x + v.y * v.y;
    #pragma unroll
    for (int off = 32; off > 0; off >>= 1) s += __shfl_xor(s, off);
    float r = 1.0f / sqrtf(s);
    float a0 = v.x * r, a1 = v.y * r;
    ushort h0 = f2bf(a0), h1 = f2bf(a1);
    ushort l0 = f2bf(a0 - bf2f(h0)), l1 = f2bf(a1 - bf2f(h1));
    ushort2 hv; hv.x = h0; hv.y = h1;
    ushort2 lv; lv.x = l0; lv.y = l1;
    reinterpret_cast<ushort2*>(dn_hi + (size_t)row * DIM)[lane] = hv;
    reinterpret_cast<ushort2*>(dn_lo + (size_t)row * DIM)[lane] = lv;
}

// ---------------- build K = 10*dot - 10 (diag -10000), MFMA split-bf16 ----------------
// 128x128 tile per block, 4 waves in 2x2, each wave 64x64 via 4x4 frags of 16x16x32.
// A/B frag layout (16x16x32 bf16): lane l holds 8 contiguous k at row (l&15), k-base (l>>4)*8.
// C/D layout: col = lane&15, row = (lane>>4)*4 + reg.
template <typename OUT>
__launch_bounds__(256, 2)
__global__ void buildK_mfma(const ushort* __restrict__ Ahi, const ushort* __restrict__ Alo,
                            OUT* __restrict__ K) {
    int tid = threadIdx.x;
    int w = tid >> 6, l = tid & 63;
    int wm = w >> 1, wn = w & 1;
    int row0 = blockIdx.y * 128 + wm * 64;
    int col0 = blockIdx.x * 128 + wn * 64;
    int lr = l & 15;
    int lk = (l >> 4) * 8;

    f32x4 acc[4][4] = {};
    #pragma unroll
    for (int ks = 0; ks < 4; ++ks) {
        int kb = ks * 32 + lk;
        bf16x8 ah[4], al[4], bh[4], bl[4];
        #pragma unroll
        for (int f = 0; f < 4; ++f) {
            size_t aoff = (size_t)(row0 + f * 16 + lr) * DIM + kb;
            size_t boff = (size_t)(col0 + f * 16 + lr) * DIM + kb;
            ah[f] = *reinterpret_cast<const bf16x8*>(Ahi + aoff);
            al[f] = *reinterpret_cast<const bf16x8*>(Alo + aoff);
            bh[f] = *reinterpret_cast<const bf16x8*>(Ahi + boff);
            bl[f] = *reinterpret_cast<const bf16x8*>(Alo + boff);
        }
        #pragma unroll
        for (int i = 0; i < 4; ++i)
            #pragma unroll
            for (int j = 0; j < 4; ++j) {
                acc[i][j] = __builtin_amdgcn_mfma_f32_16x16x32_bf16(al[i], bh[j], acc[i][j], 0, 0, 0);
                acc[i][j] = __builtin_amdgcn_mfma_f32_16x16x32_bf16(ah[i], bl[j], acc[i][j], 0, 0, 0);
                acc[i][j] = __builtin_amdgcn_mfma_f32_16x16x32_bf16(ah[i], bh[j], acc[i][j], 0, 0, 0);
            }
    }

    int orow = (l >> 4) * 4;
    #pragma unroll
    for (int i = 0; i < 4; ++i)
        #pragma unroll
        for (int j = 0; j < 4; ++j)
            #pragma unroll
            for (int r = 0; r < 4; ++r) {
                int gr = row0 + i * 16 + orow + r;
                int gc = col0 + j * 16 + lr;
                float kv = 10.0f * acc[i][j][r] - 10.0f;
                if (gr == gc) kv = -10000.0f;
                K[(size_t)gr * NROW + gc] = (OUT)kv;
            }
}

// ---------------- row LSE (fp32 K): out[i] = -log(sum_j exp(K[i][j] + vin[j])) ----------------
__launch_bounds__(256)
__global__ void lse_kernel(const float* __restrict__ K, const float* __restrict__ vin,
                           float* __restrict__ out, float* __restrict__ rmax) {
    int row = blockIdx.x;
    int tid = threadIdx.x;
    const float4* Krow = reinterpret_cast<const float4*>(K + (size_t)row * NROW);
    const float4* V4 = reinterpret_cast<const float4*>(vin);
    float s = 0.0f;
    float m = -3.4e38f;
    #pragma unroll
    for (int w = 0; w < 8; ++w) {
        int j4 = tid + w * 256;
        float4 kk = Krow[j4];
        float4 vv = V4[j4];
        float x0 = kk.x + vv.x, x1 = kk.y + vv.y, x2 = kk.z + vv.z, x3 = kk.w + vv.w;
        s += __expf(x0) + __expf(x1) + __expf(x2) + __expf(x3);
        m = fmaxf(m, fmaxf(fmaxf(x0, x1), fmaxf(x2, x3)));
    }
    #pragma unroll
    for (int off = 32; off > 0; off >>= 1) {
        s += __shfl_xor(s, off);
        m = fmaxf(m, __shfl_xor(m, off));
    }
    __shared__ float ls[4], lm[4];
    int wid = tid >> 6;
    if ((tid & 63) == 0) { ls[wid] = s; lm[wid] = m; }
    __syncthreads();
    if (tid == 0) {
        float S = ls[0] + ls[1] + ls[2] + ls[3];
        float M = fmaxf(fmaxf(lm[0], lm[1]), fmaxf(lm[2], lm[3]));
        out[row] = -__logf(S);
        rmax[row] = M;
    }
}

// ---------------- row LSE (fp16 K) ----------------
__launch_bounds__(256)
__global__ void lse16_kernel(const _Float16* __restrict__ K, const float* __restrict__ vin,
                             float* __restrict__ out, float* __restrict__ rmax) {
    int row = blockIdx.x;
    int tid = threadIdx.x;
    const half8* Krow = reinterpret_cast<const half8*>(K + (size_t)row * NROW);
    const float4* V4 = reinterpret_cast<const float4*>(vin);
    float s = 0.0f;
    float m = -3.4e38f;
    #pragma unroll
    for (int w = 0; w < 4; ++w) {
        int j8 = tid + w * 256;
        half8 kk = Krow[j8];
        float4 v0 = V4[j8 * 2];
        float4 v1 = V4[j8 * 2 + 1];
        float x0 = (float)kk[0] + v0.x, x1 = (float)kk[1] + v0.y;
        float x2 = (float)kk[2] + v0.z, x3 = (float)kk[3] + v0.w;
        float x4 = (float)kk[4] + v1.x, x5 = (float)kk[5] + v1.y;
        float x6 = (float)kk[6] + v1.z, x7 = (float)kk[7] + v1.w;
        s += __expf(x0) + __expf(x1) + __expf(x2) + __expf(x3)
           + __expf(x4) + __expf(x5) + __expf(x6) + __expf(x7);
        m = fmaxf(m, fmaxf(fmaxf(fmaxf(x0, x1), fmaxf(x2, x3)),
                           fmaxf(fmaxf(x4, x5), fmaxf(x6, x7))));
    }
    #pragma unroll
    for (int off = 32; off > 0; off >>= 1) {
        s += __shfl_xor(s, off);
        m = fmaxf(m, __shfl_xor(m, off));
    }
    __shared__ float ls[4], lm[4];
    int wid = tid >> 6;
    if ((tid & 63) == 0) { ls[wid] = s; lm[wid] = m; }
    __syncthreads();
    if (tid == 0) {
        float S = ls[0] + ls[1] + ls[2] + ls[3];
        float M = fmaxf(fmaxf(lm[0], lm[1]), fmaxf(lm[2], lm[3]));
        out[row] = -__logf(S);
        rmax[row] = M;
    }
}

// ---------------- global max of (v[j] + rmax[j]) -> 1/sigmoid(max) ----------------
__global__ void maxred_kernel(const float* __restrict__ v, const float* __restrict__ rmax,
                              float* __restrict__ sc) {
    int tid = threadIdx.x;
    float m = -3.4e38f;
    for (int j = tid; j < NROW; j += 256) m = fmaxf(m, v[j] + rmax[j]);
    #pragma unroll
    for (int off = 32; off > 0; off >>= 1) m = fmaxf(m, __shfl_xor(m, off));
    __shared__ float lm[4];
    int wid = tid >> 6;
    if ((tid & 63) == 0) lm[wid] = m;
    __syncthreads();
    if (tid == 0) {
        float M = fmaxf(fmaxf(lm[0], lm[1]), fmaxf(lm[2], lm[3]));
        sc[0] = 1.0f + __expf(-M);   // 1 / sigmoid(M)
    }
}

// ---------------- finalize (fp32 K in place) ----------------
__launch_bounds__(256)
__global__ void finalize_kernel(float* __restrict__ K, const float* __restrict__ u,
                                const float* __restrict__ v, const float* __restrict__ sc) {
    float s_inv = sc[0];
    const size_t nt4 = (size_t)NROW * NROW / 4;
    size_t stride = (size_t)gridDim.x * blockDim.x;
    for (size_t e = (size_t)blockIdx.x * blockDim.x + threadIdx.x; e < nt4; e += stride) {
        size_t i = e >> 11;
        int j0 = (int)((e & 2047) << 2);
        float4 kk = reinterpret_cast<const float4*>(K)[e];
        float4 vv = reinterpret_cast<const float4*>(v)[e & 2047];
        float ui = u[i];
        float x[4];
        x[0] = ui + kk.x + vv.x;
        x[1] = ui + kk.y + vv.y;
        x[2] = ui + kk.z + vv.z;
        x[3] = ui + kk.w + vv.w;
        float o[4];
        #pragma unroll
        for (int t = 0; t < 4; ++t)
            o[t] = s_inv * __builtin_amdgcn_rcpf(1.0f + __expf(-x[t]));
        if (i >= (size_t)j0 && i < (size_t)j0 + 4) o[i - j0] = 1.0f;
        float4 ov; ov.x = o[0]; ov.y = o[1]; ov.z = o[2]; ov.w = o[3];
        reinterpret_cast<float4*>(K)[e] = ov;
    }
}

// ---------------- finalize (fp16 K -> fp32 out) ----------------
__launch_bounds__(256)
__global__ void finalize16_kernel(const _Float16* __restrict__ K, float* __restrict__ out,
                                  const float* __restrict__ u, const float* __restrict__ v,
                                  const float* __restrict__ sc) {
    float s_inv = sc[0];
    const size_t nt8 = (size_t)NROW * NROW / 8;
    size_t stride = (size_t)gridDim.x * blockDim.x;
    for (size_t e = (size_t)blockIdx.x * blockDim.x + threadIdx.x; e < nt8; e += stride) {
        size_t i = e >> 10;                 // 1024 half8 per row
        int j0 = (int)((e & 1023) << 3);
        half8 kk = reinterpret_cast<const half8*>(K)[e];
        float4 v0 = reinterpret_cast<const float4*>(v)[(e & 1023) * 2];
        float4 v1 = reinterpret_cast<const float4*>(v)[(e & 1023) * 2 + 1];
        float ui = u[i];
        float x[8];
        x[0] = ui + (float)kk[0] + v0.x; x[1] = ui + (float)kk[1] + v0.y;
        x[2] = ui + (float)kk[2] + v0.z; x[3] = ui + (float)kk[3] + v0.w;
        x[4] = ui + (float)kk[4] + v1.x; x[5] = ui + (float)kk[5] + v1.y;
        x[6] = ui + (float)kk[6] + v1.z; x[7] = ui + (float)kk[7] + v1.w;
        float o[8];
        #pragma unroll
        for (int t = 0; t < 8; ++t)
            o[t] = s_inv * __builtin_amdgcn_rcpf(1.0f + __expf(-x[t]));
        if (i >= (size_t)j0 && i < (size_t)j0 + 8) o[i - j0] = 1.0f;
        float4 oa; oa.x = o[0]; oa.y = o[1]; oa.z = o[2]; oa.w = o[3];
        float4 ob; ob.x = o[4]; ob.y = o[5]; ob.z = o[6]; ob.w = o[7];
        reinterpret_cast<float4*>(out)[e * 2] = oa;
        reinterpret_cast<float4*>(out)[e * 2 + 1] = ob;
    }
}

extern "C" void kernel_launch(void* const* d_in, const int* in_sizes, int n_in,
                              void* d_out, int out_size, void* d_ws, size_t ws_size,
                              hipStream_t stream) {
    const float* X = (const float*)d_in[0];
    float* out = (float*)d_out;
    char* ws = (char*)d_ws;

    size_t off = 0;
    ushort* dn_hi = (ushort*)(ws + off); off += (size_t)NROW * DIM * 2;   // 2 MB
    ushort* dn_lo = (ushort*)(ws + off); off += (size_t)NROW * DIM * 2;   // 2 MB
    float* u    = (float*)(ws + off); off += NROW * 4;
    float* v    = (float*)(ws + off); off += NROW * 4;
    float* rmax = (float*)(ws + off); off += NROW * 4;
    float* sc   = (float*)(ws + off); off += 256;                          // keep 16B-align headroom
    off = (off + 255) & ~(size_t)255;
    _Float16* K16 = (_Float16*)(ws + off);
    size_t need16 = off + (size_t)NROW * NROW * 2;                         // +128 MiB

    hipMemsetAsync(v, 0, NROW * sizeof(float), stream);
    rownorm_kernel<<<NROW, 64, 0, stream>>>(X, dn_hi, dn_lo);

    dim3 g(NROW / 128, NROW / 128);
    if (ws_size >= need16) {
        buildK_mfma<_Float16><<<g, 256, 0, stream>>>(dn_hi, dn_lo, K16);
        for (int it = 0; it < 10; ++it) {
            lse16_kernel<<<NROW, 256, 0, stream>>>(K16, v, u, rmax);
            lse16_kernel<<<NROW, 256, 0, stream>>>(K16, u, v, rmax);
        }
        maxred_kernel<<<1, 256, 0, stream>>>(v, rmax, sc);
        finalize16_kernel<<<4096, 256, 0, stream>>>(K16, out, u, v, sc);
    } else {
        buildK_mfma<float><<<g, 256, 0, stream>>>(dn_hi, dn_lo, out);
        for (int it = 0; it < 10; ++it) {
            lse_kernel<<<NROW, 256, 0, stream>>>(out, v, u, rmax);
            lse_kernel<<<NROW, 256, 0, stream>>>(out, u, v, rmax);
        }
        maxred_kernel<<<1, 256, 0, stream>>>(v, rmax, sc);
        finalize_kernel<<<4096, 256, 0, stream>>>(out, u, v, sc);
    }
}